// Round 13
// baseline (183.944 us; speedup 1.0000x reference)
//
#include <hip/hip_runtime.h>
#include <hip/hip_bf16.h>
#include <stdint.h>

#define S_LEN 2048
#define D_DIM 1024
#define NROW 4096

typedef __attribute__((ext_vector_type(8))) short short8;
typedef __attribute__((ext_vector_type(4))) float f32x4;
typedef __attribute__((ext_vector_type(4))) int i32x4;
typedef __attribute__((ext_vector_type(8))) _Float16 h8;
typedef unsigned short ushort_t;

__device__ __forceinline__ ushort_t f2bf(float f) {
  uint32_t u = __float_as_uint(f);
  u += 0x7fffu + ((u >> 16) & 1u);
  return (ushort_t)(u >> 16);
}

__device__ __forceinline__ ushort_t f2h(float f) {
  _Float16 h = (_Float16)f;
  return __builtin_bit_cast(ushort_t, h);
}

__device__ __forceinline__ void gload16(const void* g, void* l) {
  __builtin_amdgcn_global_load_lds((const __attribute__((address_space(1))) void*)g,
                                   (__attribute__((address_space(3))) void*)l, 16, 0, 0);
}

// ---------------- convert fp32 -> bf16: x + Wq|Wk|Wv (contiguous) ----------
__global__ void convert4_kernel(const float* __restrict__ x,
                                const float* __restrict__ wq, const float* __restrict__ wk,
                                const float* __restrict__ wv,
                                ushort_t* __restrict__ xb, ushort_t* __restrict__ wcat) {
  const float* src; ushort_t* dst; int n;
  switch (blockIdx.y) {
    case 0: src = x;  dst = xb;             n = NROW * D_DIM;  break;
    case 1: src = wq; dst = wcat;           n = D_DIM * D_DIM; break;
    case 2: src = wk; dst = wcat + 1048576; n = D_DIM * D_DIM; break;
    default: src = wv; dst = wcat + 2097152; n = D_DIM * D_DIM; break;
  }
  int base = (blockIdx.x * 256 + threadIdx.x) * 8;
  if (base >= n) return;
  f32x4 va = *(const f32x4*)(src + base);
  f32x4 vb = *(const f32x4*)(src + base + 4);
  short8 o;
  o[0] = (short)f2bf(va[0]); o[1] = (short)f2bf(va[1]);
  o[2] = (short)f2bf(va[2]); o[3] = (short)f2bf(va[3]);
  o[4] = (short)f2bf(vb[0]); o[5] = (short)f2bf(vb[1]);
  o[6] = (short)f2bf(vb[2]); o[7] = (short)f2bf(vb[3]);
  *(short8*)(dst + base) = o;
}

__global__ void convert_wo_kernel(const float* __restrict__ wo, ushort_t* __restrict__ wob) {
  int base = (blockIdx.x * 256 + threadIdx.x) * 8;
  f32x4 va = *(const f32x4*)(wo + base);
  f32x4 vb = *(const f32x4*)(wo + base + 4);
  short8 o;
  o[0] = (short)f2bf(va[0]); o[1] = (short)f2bf(va[1]);
  o[2] = (short)f2bf(va[2]); o[3] = (short)f2bf(va[3]);
  o[4] = (short)f2bf(vb[0]); o[5] = (short)f2bf(vb[1]);
  o[6] = (short)f2bf(vb[2]); o[7] = (short)f2bf(vb[3]);
  *(short8*)(wob + base) = o;
}

// ---------------- M -> fp16 fragment-tiled M2 ------------------------------
// M2 chunk index cidx = ((combo*32 + kt)*8 + w)*64 + lane ; 16 halfs per chunk
// elem e = nf*4+r = M[b][q0i*128 + w*16 + (lane&15)][kt*64 + nf*16 + (lane>>4)*4 + r]
__global__ __launch_bounds__(256) void m2_transform(const float* __restrict__ M,
                                                    ushort_t* __restrict__ M2) {
  int tid = blockIdx.x * 256 + threadIdx.x;       // 524288 total
  int lane = tid & 63, w = (tid >> 6) & 7, kt = (tid >> 9) & 31, combo = tid >> 14;
  int c0 = lane & 15, g = lane >> 4;
  int b = combo >> 4, q0i = combo & 15;
  const float* src = M + ((size_t)b * 2048 + q0i * 128 + w * 16 + c0) * 2048 + kt * 64 + g * 4;
  ushort_t outv[16];
#pragma unroll
  for (int nf = 0; nf < 4; ++nf) {
    f32x4 v = *(const f32x4*)(src + nf * 16);
#pragma unroll
    for (int r = 0; r < 4; ++r)
      outv[nf * 4 + r] = f2h(v[r]);
  }
  *(short8*)(M2 + (size_t)tid * 16)     = *(short8*)&outv[0];
  *(short8*)(M2 + (size_t)tid * 16 + 8) = *(short8*)&outv[8];
}

// ---------------- GEMM with global_load_lds staging ------------------------
// A[4096,1024]*Bw[NB,1024]^T. MODE 0: merged QKV epilogue (NB=3072), Q
// pre-scaled by 0.125 (sm_scale). MODE 2: fp32 row-major (NB=1024).
template<int MODE>
__global__ __launch_bounds__(256, 4) void gemm_glds(const ushort_t* __restrict__ A,
                                                    const ushort_t* __restrict__ Bw,
                                                    const float* __restrict__ bias0,
                                                    const float* __restrict__ bias1,
                                                    const float* __restrict__ bias2,
                                                    void* __restrict__ Cout) {
  __shared__ ushort_t As[128 * 64];
  __shared__ ushort_t Bs[128 * 64];
  const int t = threadIdx.x;
  const int lane = t & 63;
  const int w = t >> 6;
  const int wm = w >> 1, wn = w & 1;
  const int m0 = blockIdx.x * 128, n0 = blockIdx.y * 128;
  const int g = lane >> 4, c0 = lane & 15;
  const int srow = lane >> 3, scol = (lane & 7) * 8;

  f32x4 acc[4][4] = {};

  for (int kt = 0; kt < 16; ++kt) {
    const int kk = kt * 64;
#pragma unroll
    for (int i = 0; i < 4; ++i) {
      gload16(A  + (size_t)(m0 + w * 32 + i * 8 + srow) * D_DIM + kk + scol, &As[(w * 32 + i * 8) * 64]);
      gload16(Bw + (size_t)(n0 + w * 32 + i * 8 + srow) * D_DIM + kk + scol, &Bs[(w * 32 + i * 8) * 64]);
    }
    asm volatile("s_waitcnt vmcnt(0)" ::: "memory");
    __syncthreads();
#pragma unroll
    for (int kc = 0; kc < 2; ++kc) {
      short8 af[4], bf[4];
#pragma unroll
      for (int mf = 0; mf < 4; ++mf)
        af[mf] = *(const short8*)&As[(wm * 64 + mf * 16 + c0) * 64 + kc * 32 + g * 8];
#pragma unroll
      for (int nf = 0; nf < 4; ++nf)
        bf[nf] = *(const short8*)&Bs[(wn * 64 + nf * 16 + c0) * 64 + kc * 32 + g * 8];
#pragma unroll
      for (int mf = 0; mf < 4; ++mf)
#pragma unroll
        for (int nf = 0; nf < 4; ++nf)
          acc[mf][nf] = __builtin_amdgcn_mfma_f32_16x16x32_bf16(af[mf], bf[nf], acc[mf][nf], 0, 0, 0);
    }
    __syncthreads();
  }

#pragma unroll
  for (int nf = 0; nf < 4; ++nf) {
    int jj = n0 + wn * 64 + nf * 16 + c0;
    float bval;
    if (MODE == 0) {
      int proj = jj >> 10, jcol = jj & 1023;
      const float* bp = (proj == 0) ? bias0 : ((proj == 1) ? bias1 : bias2);
      bval = bp[jcol];
    } else {
      bval = bias0[jj];
    }
#pragma unroll
    for (int mf = 0; mf < 4; ++mf) {
#pragma unroll
      for (int r = 0; r < 4; ++r) {
        int ii = m0 + wm * 64 + mf * 16 + g * 4 + r;
        float v = acc[mf][nf][r] + bval;
        if (MODE == 2) {
          ((float*)Cout)[(size_t)ii * D_DIM + jj] = v;
        } else {
          int proj = jj >> 10, jcol = jj & 1023;
          if (proj == 0) v *= 0.125f;                    // fold sm_scale into Q
          int bb = ii >> 11, s = ii & 2047;
          size_t addr;
          if (proj < 2) {
            int hcol = jcol >> 6, hd = jcol & 63;
            addr = (size_t)proj * 4194304 + ((size_t)(bb * 16 + hcol) * 2048 + s) * 64 + hd;
          } else {
            addr = (size_t)2 * 4194304 + ((size_t)bb * 1024 + jcol) * 2048 + s;   // V^T (b,h,hd,s)
          }
          ((ushort_t*)Cout)[addr] = f2bf(v);
        }
      }
    }
  }
}

// ---------------- fused masked attention -----------------------------------
// r5-proven math (__expf, scalar dpe) + quad-buffered K/V: 2 KV-tiles per
// barrier (16 barriers instead of 32). LDS 72KB; grid 512 caps residency at
// 2 blocks/CU anyway, so the extra LDS is free.
__global__ __launch_bounds__(512, 4) void attn_kernel(const ushort_t* __restrict__ Qg,
                                                      const ushort_t* __restrict__ Kg,
                                                      const ushort_t* __restrict__ Vtg,
                                                      const ushort_t* __restrict__ M2,
                                                      ushort_t* __restrict__ aout) {
  __shared__ ushort_t Ks[4][64 * 72];
  __shared__ ushort_t Vts[4][64 * 72];

  const int t = threadIdx.x, lane = t & 63, w = t >> 6;
  const int g = lane >> 4, c0 = lane & 15;
  const int id = blockIdx.x;
  const int r8 = id & 7, hh = (id >> 3) & 15, ss = id >> 7;
  const int combo = r8 + 8 * ss, b = combo >> 4, q0 = (combo & 15) * 128;
  const int bh = b * 16 + hh;

  const ushort_t* Qbase  = Qg  + ((size_t)bh * 2048 + q0) * 64;
  const ushort_t* Kbase  = Kg  + (size_t)bh * 2048 * 64;
  const ushort_t* Vtbase = Vtg + (size_t)bh * 64 * 2048;
  const ushort_t* M2base = M2 + ((size_t)combo * 32 * 8 + w) * 64 * 16 + (size_t)lane * 16;

  short8 qf[2];
#pragma unroll
  for (int kc = 0; kc < 2; ++kc)
    qf[kc] = *(const short8*)(Qbase + (size_t)(w * 16 + c0) * 64 + kc * 32 + g * 8);

  f32x4 o[4] = {};
  float dpe = 0.f;
  const int idxA = (((g & 1) * 2 + (g >> 1)) * 16 + c0) * 4;
  const int idxB = (((g & 1) * 2 + 1 - (g >> 1)) * 16 + c0) * 4;
  const bool glo = (g < 2);
  const bool gb = (g & 1);

  const int srow = t >> 3, sc8 = (t & 7) * 8;   // 512 threads cover 64x64 in one pass

  // COMPUTE one KV tile from LDS buffer `bidx` with mask regs RM0/RM1
#define COMPUTE_TILE(bidx, RM0, RM1) { \
    f32x4 sf[4] = {}; \
    _Pragma("unroll") for (int kc = 0; kc < 2; ++kc) { \
      short8 kf[4]; \
      _Pragma("unroll") for (int nf = 0; nf < 4; ++nf) \
        kf[nf] = *(const short8*)&Ks[bidx][(nf * 16 + c0) * 72 + kc * 32 + g * 8]; \
      _Pragma("unroll") for (int nf = 0; nf < 4; ++nf) \
        sf[nf] = __builtin_amdgcn_mfma_f32_16x16x32_bf16(kf[nf], qf[kc], sf[nf], 0, 0, 0); \
    } \
    h8 mh0 = __builtin_bit_cast(h8, RM0); \
    h8 mh1 = __builtin_bit_cast(h8, RM1); \
    uint32_t w4[4][2]; \
    _Pragma("unroll") for (int nf = 0; nf < 4; ++nf) { \
      float p[4]; \
      _Pragma("unroll") for (int r = 0; r < 4; ++r) { \
        float m = (nf < 2) ? (float)mh0[nf * 4 + r] : (float)mh1[(nf - 2) * 4 + r]; \
        float e = __expf(sf[nf][r] * m); \
        float pe = m * e; \
        dpe += pe; \
        p[r] = pe; \
      } \
      asm("v_cvt_pk_bf16_f32 %0, %1, %2" : "=v"(w4[nf][0]) : "v"(p[0]), "v"(p[1])); \
      asm("v_cvt_pk_bf16_f32 %0, %1, %2" : "=v"(w4[nf][1]) : "v"(p[2]), "v"(p[3])); \
    } \
    short8 pf[2]; \
    _Pragma("unroll") for (int kc = 0; kc < 2; ++kc) { \
      uint32_t sA0 = gb ? w4[2 * kc + 1][0] : w4[2 * kc][0]; \
      uint32_t sA1 = gb ? w4[2 * kc + 1][1] : w4[2 * kc][1]; \
      uint32_t sB0 = gb ? w4[2 * kc][0]     : w4[2 * kc + 1][0]; \
      uint32_t sB1 = gb ? w4[2 * kc][1]     : w4[2 * kc + 1][1]; \
      uint32_t rA0 = (uint32_t)__builtin_amdgcn_ds_bpermute(idxA, (int)sA0); \
      uint32_t rA1 = (uint32_t)__builtin_amdgcn_ds_bpermute(idxA, (int)sA1); \
      uint32_t rB0 = (uint32_t)__builtin_amdgcn_ds_bpermute(idxB, (int)sB0); \
      uint32_t rB1 = (uint32_t)__builtin_amdgcn_ds_bpermute(idxB, (int)sB1); \
      i32x4 f4; \
      f4[0] = (int)(glo ? rA0 : rB0); \
      f4[1] = (int)(glo ? rA1 : rB1); \
      f4[2] = (int)(glo ? rB0 : rA0); \
      f4[3] = (int)(glo ? rB1 : rA1); \
      pf[kc] = __builtin_bit_cast(short8, f4); \
    } \
    _Pragma("unroll") for (int kc = 0; kc < 2; ++kc) { \
      _Pragma("unroll") for (int df = 0; df < 4; ++df) { \
        short8 vf = *(const short8*)&Vts[bidx][(df * 16 + c0) * 72 + kc * 32 + g * 8]; \
        o[df] = __builtin_amdgcn_mfma_f32_16x16x32_bf16(vf, pf[kc], o[df], 0, 0, 0); \
      } \
    } }

  // prologue: stage tiles 0 and 1 into bufs 0,1 ; load their masks
  short8 rmA0, rmA1, rmB0, rmB1;
  {
    short8 k0 = *(const short8*)(Kbase + (size_t)srow * 64 + sc8);
    short8 v0 = *(const short8*)(Vtbase + (size_t)srow * 2048 + sc8);
    short8 k1 = *(const short8*)(Kbase + (size_t)(64 + srow) * 64 + sc8);
    short8 v1 = *(const short8*)(Vtbase + (size_t)srow * 2048 + 64 + sc8);
    *(short8*)&Ks[0][srow * 72 + sc8]  = k0;
    *(short8*)&Vts[0][srow * 72 + sc8] = v0;
    *(short8*)&Ks[1][srow * 72 + sc8]  = k1;
    *(short8*)&Vts[1][srow * 72 + sc8] = v1;
    rmA0 = *(const short8*)(M2base);
    rmA1 = *(const short8*)(M2base + 8);
    rmB0 = *(const short8*)(M2base + 8192);
    rmB1 = *(const short8*)(M2base + 8192 + 8);
  }
  __syncthreads();

  for (int kt = 0; kt < 32; kt += 2) {
    short8 rk2, rv2, rk3, rv3, rmA0n, rmA1n, rmB0n, rmB1n;
    if (kt < 30) {
      const int k2 = (kt + 2) * 64, k3 = (kt + 3) * 64;
      rk2 = *(const short8*)(Kbase + (size_t)(k2 + srow) * 64 + sc8);
      rv2 = *(const short8*)(Vtbase + (size_t)srow * 2048 + k2 + sc8);
      rk3 = *(const short8*)(Kbase + (size_t)(k3 + srow) * 64 + sc8);
      rv3 = *(const short8*)(Vtbase + (size_t)srow * 2048 + k3 + sc8);
      rmA0n = *(const short8*)(M2base + (size_t)(kt + 2) * 8192);
      rmA1n = *(const short8*)(M2base + (size_t)(kt + 2) * 8192 + 8);
      rmB0n = *(const short8*)(M2base + (size_t)(kt + 3) * 8192);
      rmB1n = *(const short8*)(M2base + (size_t)(kt + 3) * 8192 + 8);
    }

    ushort_t* KsA = &Ks[kt & 3][0];        // LDS pointer arith (not reg-array idx)
    ushort_t* VtA = &Vts[kt & 3][0];
    ushort_t* KsB = &Ks[(kt + 1) & 3][0];
    ushort_t* VtB = &Vts[(kt + 1) & 3][0];
    // re-express COMPUTE_TILE on raw pointers:
#define COMPUTE_TILE_P(KP, VP, RM0, RM1) { \
    f32x4 sf[4] = {}; \
    _Pragma("unroll") for (int kc = 0; kc < 2; ++kc) { \
      short8 kf[4]; \
      _Pragma("unroll") for (int nf = 0; nf < 4; ++nf) \
        kf[nf] = *(const short8*)&KP[(nf * 16 + c0) * 72 + kc * 32 + g * 8]; \
      _Pragma("unroll") for (int nf = 0; nf < 4; ++nf) \
        sf[nf] = __builtin_amdgcn_mfma_f32_16x16x32_bf16(kf[nf], qf[kc], sf[nf], 0, 0, 0); \
    } \
    h8 mh0 = __builtin_bit_cast(h8, RM0); \
    h8 mh1 = __builtin_bit_cast(h8, RM1); \
    uint32_t w4[4][2]; \
    _Pragma("unroll") for (int nf = 0; nf < 4; ++nf) { \
      float p[4]; \
      _Pragma("unroll") for (int r = 0; r < 4; ++r) { \
        float m = (nf < 2) ? (float)mh0[nf * 4 + r] : (float)mh1[(nf - 2) * 4 + r]; \
        float e = __expf(sf[nf][r] * m); \
        float pe = m * e; \
        dpe += pe; \
        p[r] = pe; \
      } \
      asm("v_cvt_pk_bf16_f32 %0, %1, %2" : "=v"(w4[nf][0]) : "v"(p[0]), "v"(p[1])); \
      asm("v_cvt_pk_bf16_f32 %0, %1, %2" : "=v"(w4[nf][1]) : "v"(p[2]), "v"(p[3])); \
    } \
    short8 pf[2]; \
    _Pragma("unroll") for (int kc = 0; kc < 2; ++kc) { \
      uint32_t sA0 = gb ? w4[2 * kc + 1][0] : w4[2 * kc][0]; \
      uint32_t sA1 = gb ? w4[2 * kc + 1][1] : w4[2 * kc][1]; \
      uint32_t sB0 = gb ? w4[2 * kc][0]     : w4[2 * kc + 1][0]; \
      uint32_t sB1 = gb ? w4[2 * kc][1]     : w4[2 * kc + 1][1]; \
      uint32_t rA0 = (uint32_t)__builtin_amdgcn_ds_bpermute(idxA, (int)sA0); \
      uint32_t rA1 = (uint32_t)__builtin_amdgcn_ds_bpermute(idxA, (int)sA1); \
      uint32_t rB0 = (uint32_t)__builtin_amdgcn_ds_bpermute(idxB, (int)sB0); \
      uint32_t rB1 = (uint32_t)__builtin_amdgcn_ds_bpermute(idxB, (int)sB1); \
      i32x4 f4; \
      f4[0] = (int)(glo ? rA0 : rB0); \
      f4[1] = (int)(glo ? rA1 : rB1); \
      f4[2] = (int)(glo ? rB0 : rA0); \
      f4[3] = (int)(glo ? rB1 : rA1); \
      pf[kc] = __builtin_bit_cast(short8, f4); \
    } \
    _Pragma("unroll") for (int kc = 0; kc < 2; ++kc) { \
      _Pragma("unroll") for (int df = 0; df < 4; ++df) { \
        short8 vf = *(const short8*)&VP[(df * 16 + c0) * 72 + kc * 32 + g * 8]; \
        o[df] = __builtin_amdgcn_mfma_f32_16x16x32_bf16(vf, pf[kc], o[df], 0, 0, 0); \
      } \
    } }

    COMPUTE_TILE_P(KsA, VtA, rmA0, rmA1);
    COMPUTE_TILE_P(KsB, VtB, rmB0, rmB1);

    if (kt < 30) {
      ushort_t* KsC = &Ks[(kt + 2) & 3][0];
      ushort_t* VtC = &Vts[(kt + 2) & 3][0];
      ushort_t* KsD = &Ks[(kt + 3) & 3][0];
      ushort_t* VtD = &Vts[(kt + 3) & 3][0];
      *(short8*)&KsC[srow * 72 + sc8] = rk2;
      *(short8*)&VtC[srow * 72 + sc8] = rv2;
      *(short8*)&KsD[srow * 72 + sc8] = rk3;
      *(short8*)&VtD[srow * 72 + sc8] = rv3;
      rmA0 = rmA0n; rmA1 = rmA1n; rmB0 = rmB0n; rmB1 = rmB1n;
    }
    __syncthreads();
  }

  // denominator: reduce across the 4 g-groups (same q = c0)
  dpe += __shfl_xor(dpe, 16);
  dpe += __shfl_xor(dpe, 32);
  float inv = 1.0f / dpe;

  // write O^T fragment: lane has O[d = df*16 + g*4 + r][q = c0]
#pragma unroll
  for (int df = 0; df < 4; ++df) {
    float v0 = o[df][0] * inv, v1 = o[df][1] * inv;
    float v2 = o[df][2] * inv, v3 = o[df][3] * inv;
    uint32_t d0, d1;
    asm("v_cvt_pk_bf16_f32 %0, %1, %2" : "=v"(d0) : "v"(v0), "v"(v1));
    asm("v_cvt_pk_bf16_f32 %0, %1, %2" : "=v"(d1) : "v"(v2), "v"(v3));
    unsigned long long pk = (unsigned long long)d0 | ((unsigned long long)d1 << 32);
    *(unsigned long long*)&aout[((size_t)b * 2048 + q0 + w * 16 + c0) * 1024 + hh * 64 + df * 16 + g * 4] = pk;
  }
#undef COMPUTE_TILE
#undef COMPUTE_TILE_P
}

// ---------------------------------------------------------------------------
extern "C" void kernel_launch(void* const* d_in, const int* in_sizes, int n_in,
                              void* d_out, int out_size, void* d_ws, size_t ws_size,
                              hipStream_t stream) {
  const float* x  = (const float*)d_in[0];
  const float* M  = (const float*)d_in[1];
  const float* Wq = (const float*)d_in[2];
  const float* bq = (const float*)d_in[3];
  const float* Wk = (const float*)d_in[4];
  const float* bk = (const float*)d_in[5];
  const float* Wv = (const float*)d_in[6];
  const float* bv = (const float*)d_in[7];
  const float* Wo = (const float*)d_in[8];
  const float* bo = (const float*)d_in[9];
  float* out = (float*)d_out;
  char* ws = (char*)d_ws;

  // ws layout (liveness-checked):
  //  [0,8M)    Qb   (qkv-gemm..attn)  ->  wob 2MB written AFTER attn (dead Qb)
  //  [8,16M)   Kb
  //  [16,24M)  Vtb
  //  [24,32M)  xb   (convert..qkv-gemm)   \  overlaid by M2 16MB [24,40M)
  //  [32,38M)  Wcat (convert..qkv-gemm)   /  (m2 runs AFTER qkv-gemm)
  //  [40,48M)  aoutb (attn..out-gemm)
  ushort_t* Qb    = (ushort_t*)(ws);
  ushort_t* Kb    = (ushort_t*)(ws + 8388608);
  ushort_t* Vtb   = (ushort_t*)(ws + 16777216);
  ushort_t* xb    = (ushort_t*)(ws + 25165824);
  ushort_t* Wcat  = (ushort_t*)(ws + 33554432);
  ushort_t* M2    = (ushort_t*)(ws + 25165824);
  ushort_t* aoutb = (ushort_t*)(ws + 41943040);
  ushort_t* wob   = (ushort_t*)(ws);               // over dead Qb, post-attn

  convert4_kernel<<<dim3(2048, 4), 256, 0, stream>>>(x, Wq, Wk, Wv, xb, Wcat);
  gemm_glds<0><<<dim3(32, 24), 256, 0, stream>>>(xb, Wcat, bq, bk, bv, (void*)Qb);
  m2_transform<<<2048, 256, 0, stream>>>(M, M2);
  attn_kernel<<<512, 512, 0, stream>>>(Qb, Kb, Vtb, M2, aoutb);
  convert_wo_kernel<<<512, 256, 0, stream>>>(Wo, wob);
  gemm_glds<2><<<dim3(32, 8), 256, 0, stream>>>(aoutb, wob, bo, bo, bo, (void*)out);
}

// Round 14
// 151.137 us; speedup vs baseline: 1.2171x; 1.2171x over previous
//
#include <hip/hip_runtime.h>
#include <hip/hip_bf16.h>
#include <stdint.h>

#define S_LEN 2048
#define D_DIM 1024
#define NROW 4096

typedef __attribute__((ext_vector_type(8))) short short8;
typedef __attribute__((ext_vector_type(4))) float f32x4;
typedef __attribute__((ext_vector_type(4))) int i32x4;
typedef __attribute__((ext_vector_type(8))) _Float16 h8;
typedef unsigned short ushort_t;

__device__ __forceinline__ ushort_t f2bf(float f) {
  uint32_t u = __float_as_uint(f);
  u += 0x7fffu + ((u >> 16) & 1u);
  return (ushort_t)(u >> 16);
}

__device__ __forceinline__ ushort_t f2h(float f) {
  _Float16 h = (_Float16)f;
  return __builtin_bit_cast(ushort_t, h);
}

__device__ __forceinline__ void gload16(const void* g, void* l) {
  __builtin_amdgcn_global_load_lds((const __attribute__((address_space(1))) void*)g,
                                   (__attribute__((address_space(3))) void*)l, 16, 0, 0);
}

// ---------------- convert fp32 -> bf16: x + Wq|Wk|Wv (contiguous) ----------
__global__ void convert4_kernel(const float* __restrict__ x,
                                const float* __restrict__ wq, const float* __restrict__ wk,
                                const float* __restrict__ wv,
                                ushort_t* __restrict__ xb, ushort_t* __restrict__ wcat) {
  const float* src; ushort_t* dst; int n;
  switch (blockIdx.y) {
    case 0: src = x;  dst = xb;             n = NROW * D_DIM;  break;
    case 1: src = wq; dst = wcat;           n = D_DIM * D_DIM; break;
    case 2: src = wk; dst = wcat + 1048576; n = D_DIM * D_DIM; break;
    default: src = wv; dst = wcat + 2097152; n = D_DIM * D_DIM; break;
  }
  int base = (blockIdx.x * 256 + threadIdx.x) * 8;
  if (base >= n) return;
  f32x4 va = *(const f32x4*)(src + base);
  f32x4 vb = *(const f32x4*)(src + base + 4);
  short8 o;
  o[0] = (short)f2bf(va[0]); o[1] = (short)f2bf(va[1]);
  o[2] = (short)f2bf(va[2]); o[3] = (short)f2bf(va[3]);
  o[4] = (short)f2bf(vb[0]); o[5] = (short)f2bf(vb[1]);
  o[6] = (short)f2bf(vb[2]); o[7] = (short)f2bf(vb[3]);
  *(short8*)(dst + base) = o;
}

__global__ void convert_wo_kernel(const float* __restrict__ wo, ushort_t* __restrict__ wob) {
  int base = (blockIdx.x * 256 + threadIdx.x) * 8;
  f32x4 va = *(const f32x4*)(wo + base);
  f32x4 vb = *(const f32x4*)(wo + base + 4);
  short8 o;
  o[0] = (short)f2bf(va[0]); o[1] = (short)f2bf(va[1]);
  o[2] = (short)f2bf(va[2]); o[3] = (short)f2bf(va[3]);
  o[4] = (short)f2bf(vb[0]); o[5] = (short)f2bf(vb[1]);
  o[6] = (short)f2bf(vb[2]); o[7] = (short)f2bf(vb[3]);
  *(short8*)(wob + base) = o;
}

// ---------------- M -> fp16 fragment-tiled M2 ------------------------------
__global__ __launch_bounds__(256) void m2_transform(const float* __restrict__ M,
                                                    ushort_t* __restrict__ M2) {
  int tid = blockIdx.x * 256 + threadIdx.x;       // 524288 total
  int lane = tid & 63, w = (tid >> 6) & 7, kt = (tid >> 9) & 31, combo = tid >> 14;
  int c0 = lane & 15, g = lane >> 4;
  int b = combo >> 4, q0i = combo & 15;
  const float* src = M + ((size_t)b * 2048 + q0i * 128 + w * 16 + c0) * 2048 + kt * 64 + g * 4;
  ushort_t outv[16];
#pragma unroll
  for (int nf = 0; nf < 4; ++nf) {
    f32x4 v = *(const f32x4*)(src + nf * 16);
#pragma unroll
    for (int r = 0; r < 4; ++r)
      outv[nf * 4 + r] = f2h(v[r]);
  }
  *(short8*)(M2 + (size_t)tid * 16)     = *(short8*)&outv[0];
  *(short8*)(M2 + (size_t)tid * 16 + 8) = *(short8*)&outv[8];
}

// ---------------- GEMM with global_load_lds staging ------------------------
template<int MODE>
__global__ __launch_bounds__(256, 4) void gemm_glds(const ushort_t* __restrict__ A,
                                                    const ushort_t* __restrict__ Bw,
                                                    const float* __restrict__ bias0,
                                                    const float* __restrict__ bias1,
                                                    const float* __restrict__ bias2,
                                                    void* __restrict__ Cout) {
  __shared__ ushort_t As[128 * 64];
  __shared__ ushort_t Bs[128 * 64];
  const int t = threadIdx.x;
  const int lane = t & 63;
  const int w = t >> 6;
  const int wm = w >> 1, wn = w & 1;
  const int m0 = blockIdx.x * 128, n0 = blockIdx.y * 128;
  const int g = lane >> 4, c0 = lane & 15;
  const int srow = lane >> 3, scol = (lane & 7) * 8;

  f32x4 acc[4][4] = {};

  for (int kt = 0; kt < 16; ++kt) {
    const int kk = kt * 64;
#pragma unroll
    for (int i = 0; i < 4; ++i) {
      gload16(A  + (size_t)(m0 + w * 32 + i * 8 + srow) * D_DIM + kk + scol, &As[(w * 32 + i * 8) * 64]);
      gload16(Bw + (size_t)(n0 + w * 32 + i * 8 + srow) * D_DIM + kk + scol, &Bs[(w * 32 + i * 8) * 64]);
    }
    asm volatile("s_waitcnt vmcnt(0)" ::: "memory");
    __syncthreads();
#pragma unroll
    for (int kc = 0; kc < 2; ++kc) {
      short8 af[4], bf[4];
#pragma unroll
      for (int mf = 0; mf < 4; ++mf)
        af[mf] = *(const short8*)&As[(wm * 64 + mf * 16 + c0) * 64 + kc * 32 + g * 8];
#pragma unroll
      for (int nf = 0; nf < 4; ++nf)
        bf[nf] = *(const short8*)&Bs[(wn * 64 + nf * 16 + c0) * 64 + kc * 32 + g * 8];
#pragma unroll
      for (int mf = 0; mf < 4; ++mf)
#pragma unroll
        for (int nf = 0; nf < 4; ++nf)
          acc[mf][nf] = __builtin_amdgcn_mfma_f32_16x16x32_bf16(af[mf], bf[nf], acc[mf][nf], 0, 0, 0);
    }
    __syncthreads();
  }

#pragma unroll
  for (int nf = 0; nf < 4; ++nf) {
    int jj = n0 + wn * 64 + nf * 16 + c0;
    float bval;
    if (MODE == 0) {
      int proj = jj >> 10, jcol = jj & 1023;
      const float* bp = (proj == 0) ? bias0 : ((proj == 1) ? bias1 : bias2);
      bval = bp[jcol];
    } else {
      bval = bias0[jj];
    }
#pragma unroll
    for (int mf = 0; mf < 4; ++mf) {
#pragma unroll
      for (int r = 0; r < 4; ++r) {
        int ii = m0 + wm * 64 + mf * 16 + g * 4 + r;
        float v = acc[mf][nf][r] + bval;
        if (MODE == 2) {
          ((float*)Cout)[(size_t)ii * D_DIM + jj] = v;
        } else {
          int proj = jj >> 10, jcol = jj & 1023;
          if (proj == 0) v *= 0.125f;                    // fold sm_scale into Q
          int bb = ii >> 11, s = ii & 2047;
          size_t addr;
          if (proj < 2) {
            int hcol = jcol >> 6, hd = jcol & 63;
            addr = (size_t)proj * 4194304 + ((size_t)(bb * 16 + hcol) * 2048 + s) * 64 + hd;
          } else {
            addr = (size_t)2 * 4194304 + ((size_t)bb * 1024 + jcol) * 2048 + s;   // V^T (b,h,hd,s)
          }
          ((ushort_t*)Cout)[addr] = f2bf(v);
        }
      }
    }
  }
}

// ---------------- fused masked attention -----------------------------------
// r5 math (__expf, scalar dpe) + T15-style intra-wave pipeline:
// tri-buffered LDS (3 x 18KB); at iter t: softmax(tile t) on VALU while
// QK^T(tile t+1) runs on MFMA (buf (t+1)%3, staged 2 barriers ago), then
// PV(t), stage tile t+2 -> buf (t+2)%3, ONE __syncthreads.
__global__ __launch_bounds__(512, 4) void attn_kernel(const ushort_t* __restrict__ Qg,
                                                      const ushort_t* __restrict__ Kg,
                                                      const ushort_t* __restrict__ Vtg,
                                                      const ushort_t* __restrict__ M2,
                                                      ushort_t* __restrict__ aout) {
  __shared__ ushort_t Ks[3][64 * 72];
  __shared__ ushort_t Vts[3][64 * 72];

  const int t = threadIdx.x, lane = t & 63, w = t >> 6;
  const int g = lane >> 4, c0 = lane & 15;
  const int id = blockIdx.x;
  const int r8 = id & 7, hh = (id >> 3) & 15, ss = id >> 7;
  const int combo = r8 + 8 * ss, b = combo >> 4, q0 = (combo & 15) * 128;
  const int bh = b * 16 + hh;

  const ushort_t* Qbase  = Qg  + ((size_t)bh * 2048 + q0) * 64;
  const ushort_t* Kbase  = Kg  + (size_t)bh * 2048 * 64;
  const ushort_t* Vtbase = Vtg + (size_t)bh * 64 * 2048;
  const ushort_t* M2base = M2 + ((size_t)combo * 32 * 8 + w) * 64 * 16 + (size_t)lane * 16;

  short8 qf[2];
#pragma unroll
  for (int kc = 0; kc < 2; ++kc)
    qf[kc] = *(const short8*)(Qbase + (size_t)(w * 16 + c0) * 64 + kc * 32 + g * 8);

  f32x4 o[4] = {};
  float dpe = 0.f;
  const int idxA = (((g & 1) * 2 + (g >> 1)) * 16 + c0) * 4;
  const int idxB = (((g & 1) * 2 + 1 - (g >> 1)) * 16 + c0) * 4;
  const bool glo = (g < 2);
  const bool gb = (g & 1);

  const int srow = t >> 3, sc8 = (t & 7) * 8;   // 512 threads cover 64x64 in one pass

  // prologue: stage tiles 0,1 into bufs 0,1 ; masks for tile 0
  {
    short8 k0 = *(const short8*)(Kbase + (size_t)srow * 64 + sc8);
    short8 v0 = *(const short8*)(Vtbase + (size_t)srow * 2048 + sc8);
    short8 k1 = *(const short8*)(Kbase + (size_t)(64 + srow) * 64 + sc8);
    short8 v1 = *(const short8*)(Vtbase + (size_t)srow * 2048 + 64 + sc8);
    *(short8*)&Ks[0][srow * 72 + sc8]  = k0;
    *(short8*)&Vts[0][srow * 72 + sc8] = v0;
    *(short8*)&Ks[1][srow * 72 + sc8]  = k1;
    *(short8*)&Vts[1][srow * 72 + sc8] = v1;
  }
  short8 rm0 = *(const short8*)(M2base);
  short8 rm1 = *(const short8*)(M2base + 8);
  __syncthreads();

  // sf for tile 0 (from buf 0)
  f32x4 sf[4] = {};
#pragma unroll
  for (int kc = 0; kc < 2; ++kc) {
    short8 kf[4];
#pragma unroll
    for (int nf = 0; nf < 4; ++nf)
      kf[nf] = *(const short8*)&Ks[0][(nf * 16 + c0) * 72 + kc * 32 + g * 8];
#pragma unroll
    for (int nf = 0; nf < 4; ++nf)
      sf[nf] = __builtin_amdgcn_mfma_f32_16x16x32_bf16(kf[nf], qf[kc], sf[nf], 0, 0, 0);
  }

  int bA = 0, bB = 1, bW = 2;   // PV/softmax buf, QK-next buf, write buf

  for (int kt = 0; kt < 32; ++kt) {
    // issue global loads for tile kt+2 and masks for tile kt+1 (latency)
    short8 rk, rv, rm0n, rm1n;
    if (kt < 30) {
      const int k2 = (kt + 2) * 64;
      rk = *(const short8*)(Kbase + (size_t)(k2 + srow) * 64 + sc8);
      rv = *(const short8*)(Vtbase + (size_t)srow * 2048 + k2 + sc8);
    }
    if (kt < 31) {
      rm0n = *(const short8*)(M2base + (size_t)(kt + 1) * 8192);
      rm1n = *(const short8*)(M2base + (size_t)(kt + 1) * 8192 + 8);
    }

    ushort_t* KB = &Ks[bB][0];
    ushort_t* VA = &Vts[bA][0];
    ushort_t* KW = &Ks[bW][0];
    ushort_t* VW = &Vts[bW][0];

    // QK^T for tile kt+1 (MFMA pipe — overlaps the exp chain below)
    f32x4 sfn[4] = {};
    if (kt < 31) {
#pragma unroll
      for (int kc = 0; kc < 2; ++kc) {
        short8 kf[4];
#pragma unroll
        for (int nf = 0; nf < 4; ++nf)
          kf[nf] = *(const short8*)&KB[(nf * 16 + c0) * 72 + kc * 32 + g * 8];
#pragma unroll
        for (int nf = 0; nf < 4; ++nf)
          sfn[nf] = __builtin_amdgcn_mfma_f32_16x16x32_bf16(kf[nf], qf[kc], sfn[nf], 0, 0, 0);
      }
    }

    // softmax(tile kt): mask * exp ; pack P to bf16 pairs
    h8 mh0 = __builtin_bit_cast(h8, rm0);
    h8 mh1 = __builtin_bit_cast(h8, rm1);
    uint32_t w4[4][2];
#pragma unroll
    for (int nf = 0; nf < 4; ++nf) {
      float p[4];
#pragma unroll
      for (int r = 0; r < 4; ++r) {
        float m = (nf < 2) ? (float)mh0[nf * 4 + r] : (float)mh1[(nf - 2) * 4 + r];
        float e = __expf(sf[nf][r] * m);
        float pe = m * e;
        dpe += pe;
        p[r] = pe;
      }
      asm("v_cvt_pk_bf16_f32 %0, %1, %2" : "=v"(w4[nf][0]) : "v"(p[0]), "v"(p[1]));
      asm("v_cvt_pk_bf16_f32 %0, %1, %2" : "=v"(w4[nf][1]) : "v"(p[2]), "v"(p[3]));
    }

    // redistribute: lane needs P[q=c0][k = kc*32 + g*8 + j]
    short8 pf[2];
#pragma unroll
    for (int kc = 0; kc < 2; ++kc) {
      uint32_t sA0 = gb ? w4[2 * kc + 1][0] : w4[2 * kc][0];
      uint32_t sA1 = gb ? w4[2 * kc + 1][1] : w4[2 * kc][1];
      uint32_t sB0 = gb ? w4[2 * kc][0]     : w4[2 * kc + 1][0];
      uint32_t sB1 = gb ? w4[2 * kc][1]     : w4[2 * kc + 1][1];
      uint32_t rA0 = (uint32_t)__builtin_amdgcn_ds_bpermute(idxA, (int)sA0);
      uint32_t rA1 = (uint32_t)__builtin_amdgcn_ds_bpermute(idxA, (int)sA1);
      uint32_t rB0 = (uint32_t)__builtin_amdgcn_ds_bpermute(idxB, (int)sB0);
      uint32_t rB1 = (uint32_t)__builtin_amdgcn_ds_bpermute(idxB, (int)sB1);
      i32x4 f4;
      f4[0] = (int)(glo ? rA0 : rB0);
      f4[1] = (int)(glo ? rA1 : rB1);
      f4[2] = (int)(glo ? rB0 : rA0);
      f4[3] = (int)(glo ? rB1 : rA1);
      pf[kc] = __builtin_bit_cast(short8, f4);
    }

    // PV: o^T[d][q] += sum_k V[k][d] * P[q][k]
#pragma unroll
    for (int kc = 0; kc < 2; ++kc) {
#pragma unroll
      for (int df = 0; df < 4; ++df) {
        short8 vf = *(const short8*)&VA[(df * 16 + c0) * 72 + kc * 32 + g * 8];
        o[df] = __builtin_amdgcn_mfma_f32_16x16x32_bf16(vf, pf[kc], o[df], 0, 0, 0);
      }
    }

    // stage tile kt+2 into write buf (its last readers finished at barrier kt-1)
    if (kt < 30) {
      *(short8*)&KW[srow * 72 + sc8] = rk;
      *(short8*)&VW[srow * 72 + sc8] = rv;
    }
    __syncthreads();

#pragma unroll
    for (int nf = 0; nf < 4; ++nf) sf[nf] = sfn[nf];
    rm0 = rm0n; rm1 = rm1n;
    int tmp = bA; bA = bB; bB = bW; bW = tmp;
  }

  // denominator: reduce across the 4 g-groups (same q = c0)
  dpe += __shfl_xor(dpe, 16);
  dpe += __shfl_xor(dpe, 32);
  float inv = 1.0f / dpe;

  // write O^T fragment: lane has O[d = df*16 + g*4 + r][q = c0]
#pragma unroll
  for (int df = 0; df < 4; ++df) {
    float v0 = o[df][0] * inv, v1 = o[df][1] * inv;
    float v2 = o[df][2] * inv, v3 = o[df][3] * inv;
    uint32_t d0, d1;
    asm("v_cvt_pk_bf16_f32 %0, %1, %2" : "=v"(d0) : "v"(v0), "v"(v1));
    asm("v_cvt_pk_bf16_f32 %0, %1, %2" : "=v"(d1) : "v"(v2), "v"(v3));
    unsigned long long pk = (unsigned long long)d0 | ((unsigned long long)d1 << 32);
    *(unsigned long long*)&aout[((size_t)b * 2048 + q0 + w * 16 + c0) * 1024 + hh * 64 + df * 16 + g * 4] = pk;
  }
}

// ---------------------------------------------------------------------------
extern "C" void kernel_launch(void* const* d_in, const int* in_sizes, int n_in,
                              void* d_out, int out_size, void* d_ws, size_t ws_size,
                              hipStream_t stream) {
  const float* x  = (const float*)d_in[0];
  const float* M  = (const float*)d_in[1];
  const float* Wq = (const float*)d_in[2];
  const float* bq = (const float*)d_in[3];
  const float* Wk = (const float*)d_in[4];
  const float* bk = (const float*)d_in[5];
  const float* Wv = (const float*)d_in[6];
  const float* bv = (const float*)d_in[7];
  const float* Wo = (const float*)d_in[8];
  const float* bo = (const float*)d_in[9];
  float* out = (float*)d_out;
  char* ws = (char*)d_ws;

  // ws layout (liveness-checked):
  //  [0,8M)    Qb   (qkv-gemm..attn)  ->  wob 2MB written AFTER attn (dead Qb)
  //  [8,16M)   Kb
  //  [16,24M)  Vtb
  //  [24,32M)  xb   (convert..qkv-gemm)   \  overlaid by M2 16MB [24,40M)
  //  [32,38M)  Wcat (convert..qkv-gemm)   /  (m2 runs AFTER qkv-gemm)
  //  [40,48M)  aoutb (attn..out-gemm)
  ushort_t* Qb    = (ushort_t*)(ws);
  ushort_t* Kb    = (ushort_t*)(ws + 8388608);
  ushort_t* Vtb   = (ushort_t*)(ws + 16777216);
  ushort_t* xb    = (ushort_t*)(ws + 25165824);
  ushort_t* Wcat  = (ushort_t*)(ws + 33554432);
  ushort_t* M2    = (ushort_t*)(ws + 25165824);
  ushort_t* aoutb = (ushort_t*)(ws + 41943040);
  ushort_t* wob   = (ushort_t*)(ws);               // over dead Qb, post-attn

  convert4_kernel<<<dim3(2048, 4), 256, 0, stream>>>(x, Wq, Wk, Wv, xb, Wcat);
  gemm_glds<0><<<dim3(32, 24), 256, 0, stream>>>(xb, Wcat, bq, bk, bv, (void*)Qb);
  m2_transform<<<2048, 256, 0, stream>>>(M, M2);
  attn_kernel<<<512, 512, 0, stream>>>(Qb, Kb, Vtb, M2, aoutb);
  convert_wo_kernel<<<512, 256, 0, stream>>>(Wo, wob);
  gemm_glds<2><<<dim3(32, 8), 256, 0, stream>>>(aoutb, wob, bo, bo, bo, (void*)out);
}